// Round 1
// baseline (471.650 us; speedup 1.0000x reference)
//
#include <hip/hip_runtime.h>

#define FLOW_DEPTH 8

// One thread per atom. w[n] is 72 contiguous floats (18 float4, 16B-aligned:
// n*288 bytes), b[n] is 24 contiguous floats (6 float4). Load everything up
// front as dwordx4, do the LU->W build and the 8-step affine chain in
// registers, write z' (3 floats) and logdet (1 float, at offset 3N).
__global__ __launch_bounds__(256) void graphflow_kernel(
    const float* __restrict__ z_in,
    const float* __restrict__ w,
    const float* __restrict__ b,
    float* __restrict__ out,
    int n_atoms)
{
    int n = blockIdx.x * blockDim.x + threadIdx.x;
    if (n >= n_atoms) return;

    float z0 = z_in[n * 3 + 0];
    float z1 = z_in[n * 3 + 1];
    float z2 = z_in[n * 3 + 2];

    // 18 float4 = 72 floats of w for this atom
    const float4* w4 = reinterpret_cast<const float4*>(w) + (size_t)n * 18;
    float4 wv[18];
#pragma unroll
    for (int i = 0; i < 18; ++i) wv[i] = w4[i];

    // 6 float4 = 24 floats of b for this atom
    const float4* b4 = reinterpret_cast<const float4*>(b) + (size_t)n * 6;
    float4 bv[6];
#pragma unroll
    for (int i = 0; i < 6; ++i) bv[i] = b4[i];

    const float* wf = reinterpret_cast<const float*>(wv);
    const float* bf = reinterpret_cast<const float*>(bv);

    float logdet = 0.0f;

#pragma unroll
    for (int d = 0; d < FLOW_DEPTH; ++d) {
        const float* W = wf + d * 9;
        float w00 = W[0], w01 = W[1], w02 = W[2];
        float w10 = W[3], w11 = W[4], w12 = W[5];
        float w20 = W[6], w21 = W[7], w22 = W[8];

        // D = |diag| + 0.1 ; log-det uses |0.1 + diag| (faithful to ref)
        float d0 = fabsf(w00) + 0.1f;
        float d1 = fabsf(w11) + 0.1f;
        float d2 = fabsf(w22) + 0.1f;
        logdet += logf(fabsf(0.1f + w00)) +
                  logf(fabsf(0.1f + w11)) +
                  logf(fabsf(0.1f + w22));

        // M = L @ (D @ U), with L = strict-lower + I, U = strict-upper + I
        // du row i: [0.. , d_i (at i,i), d_i * w_ij (j>i)]
        float m01 = d0 * w01;
        float m02 = d0 * w02;
        float m12 = d1 * w12;
        float M00 = d0;
        float M01 = m01;
        float M02 = m02;
        float M10 = w10 * d0;
        float M11 = fmaf(w10, m01, d1);
        float M12 = fmaf(w10, m02, m12);
        float M20 = w20 * d0;
        float M21 = fmaf(w20, m01, w21 * d1);
        float M22 = fmaf(w20, m02, fmaf(w21, m12, d2));

        // z = z @ M + b[d]
        float t0 = fmaf(z0, M00, fmaf(z1, M10, fmaf(z2, M20, bf[d * 3 + 0])));
        float t1 = fmaf(z0, M01, fmaf(z1, M11, fmaf(z2, M21, bf[d * 3 + 1])));
        float t2 = fmaf(z0, M02, fmaf(z1, M12, fmaf(z2, M22, bf[d * 3 + 2])));

        // z = z @ perms[d % 3]
        int p = d % 3;
        if (p == 0) {            // P_XY: (t0,t1,t2) -> (t1,t0,t2)
            z0 = t1; z1 = t0; z2 = t2;
        } else if (p == 1) {     // P_YZ: (t0,t1,t2) -> (t2,t0,t1)
            z0 = t2; z1 = t0; z2 = t1;
        } else {                 // P_XZ: (t0,t1,t2) -> (t2,t1,t0)
            z0 = t2; z1 = t1; z2 = t0;
        }
    }

    out[n * 3 + 0] = z0;
    out[n * 3 + 1] = z1;
    out[n * 3 + 2] = z2;
    out[(size_t)3 * n_atoms + n] = logdet;
}

extern "C" void kernel_launch(void* const* d_in, const int* in_sizes, int n_in,
                              void* d_out, int out_size, void* d_ws, size_t ws_size,
                              hipStream_t stream) {
    const float* z = (const float*)d_in[0];
    const float* w = (const float*)d_in[1];
    const float* b = (const float*)d_in[2];
    float* out = (float*)d_out;

    int n_atoms = in_sizes[0] / 3;  // z is [N,3]
    const int block = 256;
    int grid = (n_atoms + block - 1) / block;

    hipLaunchKernelGGL(graphflow_kernel, dim3(grid), dim3(block), 0, stream,
                       z, w, b, out, n_atoms);
}

// Round 2
// 447.717 us; speedup vs baseline: 1.0535x; 1.0535x over previous
//
#include <hip/hip_runtime.h>

#define FLOW_DEPTH 8
#define BLOCK 64        // threads == atoms per block; single wave per block
#define W_F4 18         // float4 per atom in w (72 floats = 288 B)
#define B_F4 6          // float4 per atom in b (24 floats = 96 B)

typedef const __attribute__((address_space(1))) void g_void;
typedef __attribute__((address_space(3))) void l_void;

// Coalesced staging: block's w is one contiguous 18 KiB global region, b is
// 6 KiB. DMA them to LDS with global_load_lds (wave-uniform LDS base +
// lane*16 -> layout must stay unpadded/global-ordered). Then each thread
// reads its own atom's 72+24 floats back via ds_read_b128 (~2x bank alias,
// hidden on the LDS pipe) and runs the 8-step LU flow chain in registers.
__global__ __launch_bounds__(BLOCK) void graphflow_kernel(
    const float* __restrict__ z_in,
    const float* __restrict__ w,
    const float* __restrict__ b,
    float* __restrict__ out,
    int n_atoms)
{
    __shared__ float4 sw[BLOCK * W_F4];   // 18 KiB
    __shared__ float4 sb[BLOCK * B_F4];   //  6 KiB

    const int t = threadIdx.x;            // lane id (single-wave block)
    const int atom0 = blockIdx.x * BLOCK;

    const float4* gw = reinterpret_cast<const float4*>(w) + (size_t)atom0 * W_F4;
    const float4* gb = reinterpret_cast<const float4*>(b) + (size_t)atom0 * B_F4;

    if (atom0 + BLOCK <= n_atoms) {
        // Full block: DMA straight to LDS, fully coalesced (lane i -> base + i*16).
#pragma unroll
        for (int k = 0; k < W_F4; ++k) {
            __builtin_amdgcn_global_load_lds((g_void*)(gw + k * BLOCK + t),
                                             (l_void*)(sw + k * BLOCK), 16, 0, 0);
        }
#pragma unroll
        for (int k = 0; k < B_F4; ++k) {
            __builtin_amdgcn_global_load_lds((g_void*)(gb + k * BLOCK + t),
                                             (l_void*)(sb + k * BLOCK), 16, 0, 0);
        }
    } else {
        // Partial tail block (not hit for N=1e6, but stay correct in general).
        int nw = (n_atoms - atom0) * W_F4;
        for (int k = 0; k < W_F4; ++k) {
            int idx = k * BLOCK + t;
            if (idx < nw) sw[idx] = gw[idx];
        }
        int nb = (n_atoms - atom0) * B_F4;
        for (int k = 0; k < B_F4; ++k) {
            int idx = k * BLOCK + t;
            if (idx < nb) sb[idx] = gb[idx];
        }
    }

    __builtin_amdgcn_s_waitcnt(0);   // drain DMA (vmcnt) before LDS reads
    __syncthreads();

    const int n = atom0 + t;
    if (n >= n_atoms) return;

    // LDS -> registers: this atom's 18 w-float4s and 6 b-float4s.
    float4 wr[W_F4];
#pragma unroll
    for (int j = 0; j < W_F4; ++j) wr[j] = sw[t * W_F4 + j];
    float4 br[B_F4];
#pragma unroll
    for (int j = 0; j < B_F4; ++j) br[j] = sb[t * B_F4 + j];

    const float* wf = reinterpret_cast<const float*>(wr);
    const float* bf = reinterpret_cast<const float*>(br);

    float z0 = z_in[n * 3 + 0];
    float z1 = z_in[n * 3 + 1];
    float z2 = z_in[n * 3 + 2];

    float logdet = 0.0f;

#pragma unroll
    for (int d = 0; d < FLOW_DEPTH; ++d) {
        const float* W = wf + d * 9;
        float w00 = W[0], w01 = W[1], w02 = W[2];
        float w10 = W[3], w11 = W[4], w12 = W[5];
        float w20 = W[6], w21 = W[7], w22 = W[8];

        // D = |diag| + 0.1 ; log-det uses |0.1 + diag| (faithful to ref)
        float d0 = fabsf(w00) + 0.1f;
        float d1 = fabsf(w11) + 0.1f;
        float d2 = fabsf(w22) + 0.1f;
        logdet += logf(fabsf(0.1f + w00)) +
                  logf(fabsf(0.1f + w11)) +
                  logf(fabsf(0.1f + w22));

        // M = L @ (D @ U), L = strict-lower + I, U = strict-upper + I
        float m01 = d0 * w01;
        float m02 = d0 * w02;
        float m12 = d1 * w12;
        float M00 = d0;
        float M01 = m01;
        float M02 = m02;
        float M10 = w10 * d0;
        float M11 = fmaf(w10, m01, d1);
        float M12 = fmaf(w10, m02, m12);
        float M20 = w20 * d0;
        float M21 = fmaf(w20, m01, w21 * d1);
        float M22 = fmaf(w20, m02, fmaf(w21, m12, d2));

        // z = z @ M + b[d]
        float t0 = fmaf(z0, M00, fmaf(z1, M10, fmaf(z2, M20, bf[d * 3 + 0])));
        float t1 = fmaf(z0, M01, fmaf(z1, M11, fmaf(z2, M21, bf[d * 3 + 1])));
        float t2 = fmaf(z0, M02, fmaf(z1, M12, fmaf(z2, M22, bf[d * 3 + 2])));

        // z = z @ perms[d % 3]
        int p = d % 3;
        if (p == 0) {            // P_XY
            z0 = t1; z1 = t0; z2 = t2;
        } else if (p == 1) {     // P_YZ
            z0 = t2; z1 = t0; z2 = t1;
        } else {                 // P_XZ
            z0 = t2; z1 = t1; z2 = t0;
        }
    }

    out[n * 3 + 0] = z0;
    out[n * 3 + 1] = z1;
    out[n * 3 + 2] = z2;
    out[(size_t)3 * n_atoms + n] = logdet;
}

extern "C" void kernel_launch(void* const* d_in, const int* in_sizes, int n_in,
                              void* d_out, int out_size, void* d_ws, size_t ws_size,
                              hipStream_t stream) {
    const float* z = (const float*)d_in[0];
    const float* w = (const float*)d_in[1];
    const float* b = (const float*)d_in[2];
    float* out = (float*)d_out;

    int n_atoms = in_sizes[0] / 3;  // z is [N,3]
    int grid = (n_atoms + BLOCK - 1) / BLOCK;

    hipLaunchKernelGGL(graphflow_kernel, dim3(grid), dim3(BLOCK), 0, stream,
                       z, w, b, out, n_atoms);
}

// Round 3
// 444.193 us; speedup vs baseline: 1.0618x; 1.0079x over previous
//
#include <hip/hip_runtime.h>

#define FLOW_DEPTH 8
#define BLOCK 64        // threads == atoms per block; single wave per block
#define W_F4 18         // float4 per atom in w (72 floats = 288 B)
#define B_F4 6          // float4 per atom in b (24 floats = 96 B)
#define CH   65         // padded LDS chunk stride in float4 (64 data + 1 pad)

typedef const __attribute__((address_space(1))) void g_void;
typedef __attribute__((address_space(3))) void l_void;

// w staged via global_load_lds DMA, 18 chunks of 64 float4, chunk-stride 65
// float4 (pad BETWEEN chunks -- compatible with DMA's wave-uniform-base +
// lane*16 layout). Readback addr for atom a elem j: i=18a+j -> sw[i + (i>>6)],
// bank-group (i+i>>6)%8 spreads over all 8 groups (vs 4 unpadded = 16-way).
// b is NOT staged (direct per-thread global loads, L1 absorbs): LDS = 18.3 KiB
// -> 8 single-wave blocks/CU (was 6 at 24.6 KiB). No __syncthreads needed:
// single wave issues its own DMA and waits vmcnt itself.
__global__ __launch_bounds__(BLOCK) void graphflow_kernel(
    const float* __restrict__ z_in,
    const float* __restrict__ w,
    const float* __restrict__ b,
    float* __restrict__ out,
    int n_atoms)
{
    __shared__ float4 sw[(W_F4 - 1) * CH + BLOCK];   // 17*65+64 = 1169 f4 = 18.3 KiB

    const int t = threadIdx.x;            // lane id == atom-within-block
    const int atom0 = blockIdx.x * BLOCK;
    const int n = atom0 + t;

    const float4* gw = reinterpret_cast<const float4*>(w) + (size_t)atom0 * W_F4;
    const bool full = (atom0 + BLOCK <= n_atoms);

    if (full) {
        // Coalesced DMA: chunk k -> LDS base sw + k*CH (+ lane*16 implicit).
#pragma unroll
        for (int k = 0; k < W_F4; ++k) {
            __builtin_amdgcn_global_load_lds((g_void*)(gw + k * BLOCK + t),
                                             (l_void*)(sw + k * CH), 16, 0, 0);
        }
    } else {
        // Partial tail block (not hit for N=1e6): regular loads into the same
        // padded layout.
        int nw = (n_atoms - atom0) * W_F4;
        for (int k = 0; k < W_F4; ++k) {
            int idx = k * BLOCK + t;
            if (idx < nw) sw[idx + (idx >> 6)] = gw[idx];
        }
        __syncthreads();   // block-uniform branch; cheap for one wave
    }

    // Issue b and z loads while the DMA is in flight.
    float4 br[B_F4];
    float z0 = 0.f, z1 = 0.f, z2 = 0.f;
    if (n < n_atoms) {
        const float4* gb = reinterpret_cast<const float4*>(b) + (size_t)n * B_F4;
#pragma unroll
        for (int j = 0; j < B_F4; ++j) br[j] = gb[j];
        z0 = z_in[n * 3 + 0];
        z1 = z_in[n * 3 + 1];
        z2 = z_in[n * 3 + 2];
    }

    __builtin_amdgcn_s_waitcnt(0);   // drain DMA before LDS reads

    if (n >= n_atoms) return;

    // LDS -> registers: atom t's 18 w-float4s from the padded layout.
    float4 wr[W_F4];
#pragma unroll
    for (int j = 0; j < W_F4; ++j) {
        int i = t * W_F4 + j;
        wr[j] = sw[i + (i >> 6)];
    }

    const float* wf = reinterpret_cast<const float*>(wr);
    const float* bf = reinterpret_cast<const float*>(br);

    float logdet = 0.0f;

#pragma unroll
    for (int d = 0; d < FLOW_DEPTH; ++d) {
        const float* W = wf + d * 9;
        float w00 = W[0], w01 = W[1], w02 = W[2];
        float w10 = W[3], w11 = W[4], w12 = W[5];
        float w20 = W[6], w21 = W[7], w22 = W[8];

        // D = |diag| + 0.1 ; log-det uses |0.1 + diag| (faithful to ref).
        float d0 = fabsf(w00) + 0.1f;
        float d1 = fabsf(w11) + 0.1f;
        float d2 = fabsf(w22) + 0.1f;
        // sum of 3 logs = log of |product|; one v_log_f32 instead of three.
        logdet += __logf(fabsf((0.1f + w00) * (0.1f + w11) * (0.1f + w22)));

        // M = L @ (D @ U), L = strict-lower + I, U = strict-upper + I
        float m01 = d0 * w01;
        float m02 = d0 * w02;
        float m12 = d1 * w12;
        float M00 = d0;
        float M01 = m01;
        float M02 = m02;
        float M10 = w10 * d0;
        float M11 = fmaf(w10, m01, d1);
        float M12 = fmaf(w10, m02, m12);
        float M20 = w20 * d0;
        float M21 = fmaf(w20, m01, w21 * d1);
        float M22 = fmaf(w20, m02, fmaf(w21, m12, d2));

        // z = z @ M + b[d]
        float t0 = fmaf(z0, M00, fmaf(z1, M10, fmaf(z2, M20, bf[d * 3 + 0])));
        float t1 = fmaf(z0, M01, fmaf(z1, M11, fmaf(z2, M21, bf[d * 3 + 1])));
        float t2 = fmaf(z0, M02, fmaf(z1, M12, fmaf(z2, M22, bf[d * 3 + 2])));

        // z = z @ perms[d % 3]
        int p = d % 3;
        if (p == 0) {            // P_XY
            z0 = t1; z1 = t0; z2 = t2;
        } else if (p == 1) {     // P_YZ
            z0 = t2; z1 = t0; z2 = t1;
        } else {                 // P_XZ
            z0 = t2; z1 = t1; z2 = t0;
        }
    }

    out[n * 3 + 0] = z0;
    out[n * 3 + 1] = z1;
    out[n * 3 + 2] = z2;
    out[(size_t)3 * n_atoms + n] = logdet;
}

extern "C" void kernel_launch(void* const* d_in, const int* in_sizes, int n_in,
                              void* d_out, int out_size, void* d_ws, size_t ws_size,
                              hipStream_t stream) {
    const float* z = (const float*)d_in[0];
    const float* w = (const float*)d_in[1];
    const float* b = (const float*)d_in[2];
    float* out = (float*)d_out;

    int n_atoms = in_sizes[0] / 3;  // z is [N,3]
    int grid = (n_atoms + BLOCK - 1) / BLOCK;

    hipLaunchKernelGGL(graphflow_kernel, dim3(grid), dim3(BLOCK), 0, stream,
                       z, w, b, out, n_atoms);
}